// Round 7
// baseline (468.209 us; speedup 1.0000x reference)
//
#include <hip/hip_runtime.h>
#include <cstdint>
#include <cstddef>

typedef unsigned short u16;
typedef __attribute__((ext_vector_type(8))) short short8;
typedef __attribute__((ext_vector_type(4))) float f32x4;

#define BB 4
#define SS 2048
#define DD 1024

__device__ __forceinline__ u16 f2bf(float f) {
  union { float f; unsigned u; } x; x.f = f;
  unsigned r = x.u + 0x7FFFu + ((x.u >> 16) & 1u);
  return (u16)(r >> 16);
}

__device__ __forceinline__ void gld_lds16(const void* g, void* l) {
  __builtin_amdgcn_global_load_lds(
      (const __attribute__((address_space(1))) void*)g,
      (__attribute__((address_space(3))) void*)l, 16, 0, 0);
}

__device__ __forceinline__ void store_out(float* p, float v) { *p = v; }
__device__ __forceinline__ void store_out(u16* p, float v) { *p = f2bf(v); }

// ---------------------------------------------------------------------------
// m201-style 4-phase GEMM, BK=64. BMx256 tile, 8 waves (2M x 4N).
// LDS double-buffered, each buf = 4 panels {Ak0, Bk0, Ak1, Bk1}.
// Per K-tile: P1 {vmcnt(LEAVE); barrier; read A(k0)+B(lo,k0); stage Ak0(t+1);
// MFMA}, P2 {read B(hi,k0); stage Bk0(t+1); MFMA}, P3/P4 mirror on k1.
// vmcnt never 0 mid-loop (LEAVE = SA+2); stage->use distance 3-4 phases.
// ALL register-array indices are compile-time static (rule #20: round-6's
// runtime `nh` arg sent the 128-reg accumulator to scratch -> 596 MB HBM
// writes). acc is split into acc0/acc1, rdB into rdBlo/rdBhi.
// LDS swizzle (both-sides involution, 0 conflicts): cbyte ^= ((row>>1)&3)<<4.
// MODE 0: C[row][col] = acc*scale (+bias[col]).
// MODE 1 (QKV, BM=256): x-blk 0-3 -> C (Q), 4-7 -> out2 (K); 8-11 (V) use
// operand-swapped MFMA -> transposed tile -> coalesced Vt[b][d][t] stores.
// Grid: x=N/256, y=M/BM, z=batch; nwg % 8 == 0. K % 64 == 0, K >= 128.
// ---------------------------------------------------------------------------
template<typename OutT, int BM, int MODE, bool HAS_BIAS>
__global__ __launch_bounds__(512, 2) void gemm8p(
    const u16* __restrict__ A, size_t sA, int ldaB,
    const u16* __restrict__ B, size_t sB, int ldbB,
    OutT* __restrict__ C, size_t sC, int ldc,
    const float* __restrict__ bias, float scale, int K,
    u16* __restrict__ out2, u16* __restrict__ out3)
{
  constexpr int MF2   = BM / 32;          // m-frags per wave (8 or 4)
  constexpr int APAN  = BM * 32;          // A panel elems (per k-half)
  constexpr int HSTEP = APAN + 8192;      // A+B panel pair
  constexpr int DBUF  = 2 * HSTEP;        // one double-buffer half
  constexpr int SA    = BM / 128;         // gld_lds per A-half stage
  constexpr int LEAVE = SA + 2;           // loads left in flight at waits
  __shared__ u16 sm[4 * HSTEP];           // 128 KB (BM=256) / 96 KB (BM=128)

  // ---- XCD-aware block swizzle (bijective: nwg % 8 == 0)
  const int gx = gridDim.x, gy = gridDim.y;
  const int nwg = gx * gy * gridDim.z;
  const int flat = blockIdx.x + gx * (blockIdx.y + gy * blockIdx.z);
  const int swz = (flat & 7) * (nwg >> 3) + (flat >> 3);
  const int bz  = swz / (gx * gy);
  const int rem = swz - bz * (gx * gy);
  const int by  = rem / gx;
  const int bx  = rem - by * gx;
  const int blockM = by * BM, blockN = bx * 256;

  const char* Abase = (const char*)(A + (size_t)bz * sA);
  const char* Bbase = (const char*)(B + (size_t)bz * sB);

  const int tid  = threadIdx.x;
  const int wave = tid >> 6, lane = tid & 63;
  const int wrow = (wave >> 2) * (BM / 2);
  const int wcol = (wave & 3) * 64;

  // ---- staging coords: thread -> (row 0..127, swizzled col-byte)
  const int sr  = tid >> 2;
  const int scb = ((tid & 3) * 16) ^ (((sr >> 1) & 3) << 4);
  const char* gA0 = Abase + (size_t)(blockM + sr) * ldaB + scb;
  const char* gA1 = (SA == 2) ? Abase + (size_t)(blockM + sr + 128) * ldaB + scb
                              : nullptr;
  const char* gB0 = Bbase + (size_t)(blockN + sr)       * ldbB + scb;
  const char* gB1 = Bbase + (size_t)(blockN + sr + 128) * ldbB + scb;
  const int ldsw = wave * 512;   // wave-uniform LDS dest base (elems)

  // stage half h (0:k0, 1:k1) of K-tile t1 into buf (t1&1)
  auto STAGEA = [&](int t1, int h) {
    u16* Ap = sm + (t1 & 1) * DBUF + h * HSTEP;
    const int kb = t1 * 128 + h * 64;
    gld_lds16(gA0 + kb, Ap + ldsw);
    if constexpr (SA == 2) gld_lds16(gA1 + kb, Ap + 4096 + ldsw);
  };
  auto STAGEB = [&](int t1, int h) {
    u16* Bp = sm + (t1 & 1) * DBUF + h * HSTEP + APAN;
    const int kb = t1 * 128 + h * 64;
    gld_lds16(gB0 + kb, Bp + ldsw);
    gld_lds16(gB1 + kb, Bp + 4096 + ldsw);
  };

  // ---- precomputed swizzled frag read offsets (elems, panel-relative)
  const int r16 = lane & 15, q8 = (lane >> 4) * 8;
  int offA[MF2];
#pragma unroll
  for (int mi = 0; mi < MF2; ++mi) {
    const int row = wrow + mi * 16 + r16;
    offA[mi] = row * 32 + (q8 ^ (((row >> 1) & 3) << 3));
  }
  int offB0, offB1, offB2, offB3;
  {
    const int r0 = wcol + 0 * 16 + r16;
    const int r1 = wcol + 1 * 16 + r16;
    const int r2 = wcol + 2 * 16 + r16;
    const int r3 = wcol + 3 * 16 + r16;
    offB0 = r0 * 32 + (q8 ^ (((r0 >> 1) & 3) << 3));
    offB1 = r1 * 32 + (q8 ^ (((r1 >> 1) & 3) << 3));
    offB2 = r2 * 32 + (q8 ^ (((r2 >> 1) & 3) << 3));
    offB3 = r3 * 32 + (q8 ^ (((r3 >> 1) & 3) << 3));
  }

  auto rdA = [&](short8* a, int d, int h) {
    const u16* P = sm + d * DBUF + h * HSTEP;
#pragma unroll
    for (int mi = 0; mi < MF2; ++mi) a[mi] = *(const short8*)(P + offA[mi]);
  };
  auto rdBlo = [&](short8* b, int d, int h) {
    const u16* P = sm + d * DBUF + h * HSTEP + APAN;
    b[0] = *(const short8*)(P + offB0);
    b[1] = *(const short8*)(P + offB1);
  };
  auto rdBhi = [&](short8* b, int d, int h) {
    const u16* P = sm + d * DBUF + h * HSTEP + APAN;
    b[0] = *(const short8*)(P + offB2);
    b[1] = *(const short8*)(P + offB3);
  };

  f32x4 acc0[MF2][2] = {};   // n-frags 0,1
  f32x4 acc1[MF2][2] = {};   // n-frags 2,3
  const bool vblk = (MODE == 1) && (blockN >= 2048);

  auto MMA = [&](short8* a2, short8* b2, f32x4 (&ac)[MF2][2]) {
    __builtin_amdgcn_s_setprio(1);
    if (vblk) {
#pragma unroll
      for (int mi = 0; mi < MF2; ++mi)
#pragma unroll
        for (int j = 0; j < 2; ++j)
          ac[mi][j] = __builtin_amdgcn_mfma_f32_16x16x32_bf16(
              b2[j], a2[mi], ac[mi][j], 0, 0, 0);
    } else {
#pragma unroll
      for (int mi = 0; mi < MF2; ++mi)
#pragma unroll
        for (int j = 0; j < 2; ++j)
          ac[mi][j] = __builtin_amdgcn_mfma_f32_16x16x32_bf16(
              a2[mi], b2[j], ac[mi][j], 0, 0, 0);
    }
    __builtin_amdgcn_s_setprio(0);
  };

  const int NT = K >> 6;   // K-tiles (BK=64)

  // ---- prologue: stage all 4 halves of tile 0 (issue order = ledger order)
  STAGEA(0, 0); STAGEB(0, 0); STAGEA(0, 1); STAGEB(0, 1);

  short8 a[MF2], bv0[2], bv1[2];
  for (int t = 0; t < NT; ++t) {
    const int d = t & 1;
    const bool more = (t + 1 < NT);

    // ---- P1 (k0, n-lo)
    asm volatile("s_waitcnt vmcnt(%0)" :: "i"(LEAVE) : "memory");
    __builtin_amdgcn_s_barrier();
    __builtin_amdgcn_sched_barrier(0);
    rdA(a, d, 0);
    rdBlo(bv0, d, 0);
    if (more) STAGEA(t + 1, 0);
    MMA(a, bv0, acc0);

    // ---- P2 (k0, n-hi) — no wait/barrier
    rdBhi(bv1, d, 0);
    if (more) STAGEB(t + 1, 0);
    MMA(a, bv1, acc1);

    // ---- P3 (k1, n-lo)
    if (more) asm volatile("s_waitcnt vmcnt(%0)" :: "i"(LEAVE) : "memory");
    else      asm volatile("s_waitcnt vmcnt(0)" ::: "memory");
    __builtin_amdgcn_s_barrier();
    __builtin_amdgcn_sched_barrier(0);
    rdA(a, d, 1);
    rdBlo(bv0, d, 1);
    if (more) STAGEA(t + 1, 1);
    MMA(a, bv0, acc0);

    // ---- P4 (k1, n-hi) — no wait/barrier
    rdBhi(bv1, d, 1);
    if (more) STAGEB(t + 1, 1);
    MMA(a, bv1, acc1);
  }

  // ---- epilogue: C/D layout col=lane&15, row=(lane>>4)*4+i
  const int cr = lane & 15, rr0 = (lane >> 4) * 4;
  OutT* Cb = C + (size_t)bz * sC;
  if (vblk) {
    // operand-swapped: D[row = W-side (d)][col = X-side (t, within M)]
#pragma unroll
    for (int nj = 0; nj < 4; ++nj) {
#pragma unroll
      for (int mi = 0; mi < MF2; ++mi) {
        f32x4 v = (nj < 2) ? acc0[mi][nj & 1] : acc1[mi][nj & 1];
        const int tg = blockM + wrow + mi * 16 + cr;   // global M row
        const int b  = tg >> 11, t0 = tg & 2047;
        const int d0 = blockN - 2048 + wcol + nj * 16 + rr0;
#pragma unroll
        for (int i = 0; i < 4; ++i) {
          const float bval = HAS_BIAS ? bias[2048 + d0 + i] : 0.0f;
          out3[((size_t)b * 1024 + d0 + i) * 2048 + t0] = f2bf(v[i] + bval);
        }
      }
    }
  } else {
#pragma unroll
    for (int nj = 0; nj < 4; ++nj) {
      const int colg = blockN + wcol + nj * 16 + cr;
      const float bval = HAS_BIAS ? bias[colg] : 0.0f;
#pragma unroll
      for (int mi = 0; mi < MF2; ++mi) {
        f32x4 v = (nj < 2) ? acc0[mi][nj & 1] : acc1[mi][nj & 1];
        const int rowg = blockM + wrow + mi * 16 + rr0;
        if constexpr (MODE == 0) {
#pragma unroll
          for (int i = 0; i < 4; ++i)
            store_out(&Cb[(size_t)(rowg + i) * ldc + colg], v[i] * scale + bval);
        } else {
          u16* dst = (colg < 1024) ? (u16*)Cb : out2;
          const int c2 = colg & 1023;
#pragma unroll
          for (int i = 0; i < 4; ++i)
            dst[(size_t)(rowg + i) * 1024 + c2] = f2bf(v[i] + bval);
        }
      }
    }
  }
}

// ---------------------------------------------------------------------------
// aux kernels
// ---------------------------------------------------------------------------
__global__ __launch_bounds__(256) void cvt_f32_bf16(
    const float* __restrict__ in, u16* __restrict__ out, int n4)
{
  int i = blockIdx.x * 256 + threadIdx.x;
  if (i >= n4) return;
  float4 v = ((const float4*)in)[i];
  uint2 u;
  u.x = (unsigned)f2bf(v.x) | ((unsigned)f2bf(v.y) << 16);
  u.y = (unsigned)f2bf(v.z) | ((unsigned)f2bf(v.w) << 16);
  ((uint2*)out)[i] = u;
}

__global__ __launch_bounds__(256) void transpose_cvt(
    const float* __restrict__ W, u16* __restrict__ Wt)
{
  __shared__ u16 tile[32][33];
  const int tx = threadIdx.x;
  const int ty = threadIdx.y;
  const int bx = blockIdx.x * 32;
  const int by = blockIdx.y * 32;
#pragma unroll
  for (int j = 0; j < 4; ++j) {
    int d = by + ty * 4 + j;
    tile[ty * 4 + j][tx] = f2bf(W[(size_t)d * DD + bx + tx]);
  }
  __syncthreads();
#pragma unroll
  for (int j = 0; j < 4; ++j) {
    int f = bx + ty * 4 + j;
    Wt[(size_t)f * DD + by + tx] = tile[tx][ty * 4 + j];
  }
}

__global__ __launch_bounds__(256) void concat_bias(
    const float* __restrict__ bq, const float* __restrict__ bk,
    const float* __restrict__ bv, float* __restrict__ out)
{
  int i = blockIdx.x * 256 + threadIdx.x;   // 3072 total
  const float* src = (i < 1024) ? bq : ((i < 2048) ? bk : bv);
  out[i] = src[i & 1023];
}

__global__ __launch_bounds__(256) void softmax_inplace(float* __restrict__ S)
{
  const int tid = threadIdx.x;
  float* rp = S + (size_t)blockIdx.x * SS;

  float4 v0 = ((const float4*)rp)[tid];
  float4 v1 = ((const float4*)rp)[tid + 256];

  float m = fmaxf(fmaxf(fmaxf(v0.x, v0.y), fmaxf(v0.z, v0.w)),
                  fmaxf(fmaxf(v1.x, v1.y), fmaxf(v1.z, v1.w)));
#pragma unroll
  for (int off = 32; off; off >>= 1) m = fmaxf(m, __shfl_xor(m, off));

  __shared__ float smax[4];
  __shared__ float ssum[4];
  const int wave = tid >> 6, lane = tid & 63;
  if (lane == 0) smax[wave] = m;
  __syncthreads();
  m = fmaxf(fmaxf(smax[0], smax[1]), fmaxf(smax[2], smax[3]));

  float e[8];
  e[0] = __expf(v0.x - m); e[1] = __expf(v0.y - m);
  e[2] = __expf(v0.z - m); e[3] = __expf(v0.w - m);
  e[4] = __expf(v1.x - m); e[5] = __expf(v1.y - m);
  e[6] = __expf(v1.z - m); e[7] = __expf(v1.w - m);
  float s = e[0] + e[1] + e[2] + e[3] + e[4] + e[5] + e[6] + e[7];
#pragma unroll
  for (int off = 32; off; off >>= 1) s += __shfl_xor(s, off);
  if (lane == 0) ssum[wave] = s;
  __syncthreads();
  float inv = 1.0f / (ssum[0] + ssum[1] + ssum[2] + ssum[3]);

  uint2 u0, u1;
  u0.x = (unsigned)f2bf(e[0] * inv) | ((unsigned)f2bf(e[1] * inv) << 16);
  u0.y = (unsigned)f2bf(e[2] * inv) | ((unsigned)f2bf(e[3] * inv) << 16);
  u1.x = (unsigned)f2bf(e[4] * inv) | ((unsigned)f2bf(e[5] * inv) << 16);
  u1.y = (unsigned)f2bf(e[6] * inv) | ((unsigned)f2bf(e[7] * inv) << 16);
  ((uint2*)rp)[tid]       = u0;
  ((uint2*)rp)[tid + 256] = u1;
}

// ---------------------------------------------------------------------------
extern "C" void kernel_launch(void* const* d_in, const int* in_sizes, int n_in,
                              void* d_out, int out_size, void* d_ws, size_t ws_size,
                              hipStream_t stream) {
  (void)in_sizes; (void)n_in; (void)out_size; (void)ws_size;
  const float* X  = (const float*)d_in[0];
  const float* Wq = (const float*)d_in[1];
  const float* bq = (const float*)d_in[2];
  const float* Wk = (const float*)d_in[3];
  const float* bk = (const float*)d_in[4];
  const float* Wv = (const float*)d_in[5];
  const float* bv = (const float*)d_in[6];
  const float* Wo = (const float*)d_in[7];
  const float* bo = (const float*)d_in[8];

  char* ws = (char*)d_ws;
  const size_t MBy = 1ull << 20;
  u16*   Xbf   = (u16*)(ws + 0);          // 16 MB [8192][1024]
  u16*   WtAll = (u16*)(ws + 16 * MBy);   //  6 MB [3072][1024]
  u16*   Wto   = (u16*)(ws + 22 * MBy);   //  2 MB [1024][1024]
  u16*   Qb    = (u16*)(ws + 24 * MBy);   // 16 MB [8192][1024]
  u16*   Kb    = (u16*)(ws + 40 * MBy);   // 16 MB
  u16*   Vt    = (u16*)(ws + 56 * MBy);   // 16 MB [4][1024][2048]
  float* Sf    = (float*)(ws + 72 * MBy); // 64 MB [4][2048][2048]
  float* bqkv  = (float*)(ws + 72 * MBy); // aliases Sf (consumed before QK^T)
  u16*   Ctx   = (u16*)(ws + 136 * MBy);  // 16 MB [8192][1024]

  // 1. conversions + packing
  cvt_f32_bf16<<<dim3((BB * SS * DD / 4) / 256), 256, 0, stream>>>(X, Xbf, BB * SS * DD / 4);
  dim3 tb(32, 8);
  transpose_cvt<<<dim3(32, 32), tb, 0, stream>>>(Wq, WtAll);
  transpose_cvt<<<dim3(32, 32), tb, 0, stream>>>(Wk, WtAll + 1024 * 1024);
  transpose_cvt<<<dim3(32, 32), tb, 0, stream>>>(Wv, WtAll + 2 * 1024 * 1024);
  transpose_cvt<<<dim3(32, 32), tb, 0, stream>>>(Wo, Wto);
  concat_bias<<<dim3(12), 256, 0, stream>>>(bq, bk, bv, bqkv);

  // 2. merged QKV projection: [8192][3072]; V via operand-swap (384 blocks)
  gemm8p<u16, 256, 1, true><<<dim3(12, 32, 1), 512, 0, stream>>>(
      Xbf, 0, DD * 2, WtAll, 0, DD * 2,
      Qb, 0, 0, bqkv, 1.0f, DD, Kb, Vt);

  // 3. scores = Q K^T / 8 (fp32, 256 blocks)
  gemm8p<float, 256, 0, false><<<dim3(8, 8, BB), 512, 0, stream>>>(
      Qb, (size_t)SS * DD, DD * 2, Kb, (size_t)SS * DD, DD * 2,
      Sf, (size_t)SS * SS, SS, nullptr, 0.125f, DD, nullptr, nullptr);

  // 4. softmax rows (in-place fp32 -> bf16)
  softmax_inplace<<<dim3(BB * SS), 256, 0, stream>>>(Sf);

  // 5. ctx = P V  (P bf16 rows of 8192 B; B = Vt [1024][2048]; 256 blocks)
  gemm8p<u16, 128, 0, false><<<dim3(4, 16, BB), 512, 0, stream>>>(
      (const u16*)Sf, (size_t)SS * 2 * SS, 2 * SS * 2,
      Vt, (size_t)DD * SS, SS * 2,
      Ctx, (size_t)SS * DD, DD, nullptr, 1.0f, SS, nullptr, nullptr);

  // 6. out = ctx Wo^T + bo (fp32, 256 blocks)
  gemm8p<float, 128, 0, true><<<dim3(4, 64, 1), 512, 0, stream>>>(
      Ctx, 0, DD * 2, Wto, 0, DD * 2,
      (float*)d_out, 0, DD, bo, 1.0f, DD, nullptr, nullptr);
}

// Round 8
// 466.208 us; speedup vs baseline: 1.0043x; 1.0043x over previous
//
#include <hip/hip_runtime.h>
#include <cstdint>
#include <cstddef>

typedef unsigned short u16;
typedef __attribute__((ext_vector_type(8))) short short8;
typedef __attribute__((ext_vector_type(4))) float f32x4;

#define BB 4
#define SS 2048
#define DD 1024

__device__ __forceinline__ u16 f2bf(float f) {
  union { float f; unsigned u; } x; x.f = f;
  unsigned r = x.u + 0x7FFFu + ((x.u >> 16) & 1u);
  return (u16)(r >> 16);
}

__device__ __forceinline__ void gld_lds16(const void* g, void* l) {
  __builtin_amdgcn_global_load_lds(
      (const __attribute__((address_space(1))) void*)g,
      (__attribute__((address_space(3))) void*)l, 16, 0, 0);
}

__device__ __forceinline__ void store_out(float* p, float v) { *p = v; }
__device__ __forceinline__ void store_out(u16* p, float v) { *p = f2bf(v); }

// ---------------------------------------------------------------------------
// m201-style 4-phase GEMM, BK=64. BMx256 tile, 8 waves (2M x 4N).
// LDS double-buffered, each buf = 4 panels {Ak0, Bk0, Ak1, Bk1}.
// Per K-tile: P1 {vmcnt(LEAVE); barrier; read A(k0)+B(lo,k0); stage Ak0(t+1);
// MFMA}, P2 {read B(hi,k0); stage Bk0(t+1); MFMA}, P3/P4 mirror on k1.
// vmcnt never 0 mid-loop (LEAVE = SA+2); stage->use distance 3-4 phases.
// LAUNCH BOUNDS: (512, 1). Rounds 6/7 used (512,2), which caps the wave at
// 128 VGPRs (16 waves/CU target); BM=256 needs 128 VGPRs for acc ALONE ->
// the whole accumulator spilled to scratch (596 MB HBM writes/dispatch,
// MfmaUtil 6%). 96-128 KB LDS already limits to 1 block/CU, so (512,2)
// bought no occupancy. (512,1) -> 256-VGPR cap, no spill.
// LDS swizzle (both-sides involution, 0 conflicts): cbyte ^= ((row>>1)&3)<<4.
// MODE 0: C[row][col] = acc*scale (+bias[col]).
// MODE 1 (QKV, BM=256): x-blk 0-3 -> C (Q), 4-7 -> out2 (K); 8-11 (V) use
// operand-swapped MFMA -> transposed tile -> coalesced Vt[b][d][t] stores.
// Grid: x=N/256, y=M/BM, z=batch; nwg % 8 == 0. K % 64 == 0, K >= 128.
// ---------------------------------------------------------------------------
template<typename OutT, int BM, int MODE, bool HAS_BIAS>
__global__ __launch_bounds__(512, 1) void gemm8p(
    const u16* __restrict__ A, size_t sA, int ldaB,
    const u16* __restrict__ B, size_t sB, int ldbB,
    OutT* __restrict__ C, size_t sC, int ldc,
    const float* __restrict__ bias, float scale, int K,
    u16* __restrict__ out2, u16* __restrict__ out3)
{
  constexpr int MF2   = BM / 32;          // m-frags per wave (8 or 4)
  constexpr int APAN  = BM * 32;          // A panel elems (per k-half)
  constexpr int HSTEP = APAN + 8192;      // A+B panel pair
  constexpr int DBUF  = 2 * HSTEP;        // one double-buffer half
  constexpr int SA    = BM / 128;         // gld_lds per A-half stage
  constexpr int LEAVE = SA + 2;           // loads left in flight at waits
  __shared__ u16 sm[4 * HSTEP];           // 128 KB (BM=256) / 96 KB (BM=128)

  // ---- XCD-aware block swizzle (bijective: nwg % 8 == 0)
  const int gx = gridDim.x, gy = gridDim.y;
  const int nwg = gx * gy * gridDim.z;
  const int flat = blockIdx.x + gx * (blockIdx.y + gy * blockIdx.z);
  const int swz = (flat & 7) * (nwg >> 3) + (flat >> 3);
  const int bz  = swz / (gx * gy);
  const int rem = swz - bz * (gx * gy);
  const int by  = rem / gx;
  const int bx  = rem - by * gx;
  const int blockM = by * BM, blockN = bx * 256;

  const char* Abase = (const char*)(A + (size_t)bz * sA);
  const char* Bbase = (const char*)(B + (size_t)bz * sB);

  const int tid  = threadIdx.x;
  const int wave = tid >> 6, lane = tid & 63;
  const int wrow = (wave >> 2) * (BM / 2);
  const int wcol = (wave & 3) * 64;

  // ---- staging coords: thread -> (row 0..127, swizzled col-byte)
  const int sr  = tid >> 2;
  const int scb = ((tid & 3) * 16) ^ (((sr >> 1) & 3) << 4);
  const char* gA0 = Abase + (size_t)(blockM + sr) * ldaB + scb;
  const char* gA1 = (SA == 2) ? Abase + (size_t)(blockM + sr + 128) * ldaB + scb
                              : nullptr;
  const char* gB0 = Bbase + (size_t)(blockN + sr)       * ldbB + scb;
  const char* gB1 = Bbase + (size_t)(blockN + sr + 128) * ldbB + scb;
  const int ldsw = wave * 512;   // wave-uniform LDS dest base (elems)

  // stage half h (0:k0, 1:k1) of K-tile t1 into buf (t1&1)
  auto STAGEA = [&](int t1, int h) {
    u16* Ap = sm + (t1 & 1) * DBUF + h * HSTEP;
    const int kb = t1 * 128 + h * 64;
    gld_lds16(gA0 + kb, Ap + ldsw);
    if constexpr (SA == 2) gld_lds16(gA1 + kb, Ap + 4096 + ldsw);
  };
  auto STAGEB = [&](int t1, int h) {
    u16* Bp = sm + (t1 & 1) * DBUF + h * HSTEP + APAN;
    const int kb = t1 * 128 + h * 64;
    gld_lds16(gB0 + kb, Bp + ldsw);
    gld_lds16(gB1 + kb, Bp + 4096 + ldsw);
  };

  // ---- precomputed swizzled frag read offsets (elems, panel-relative)
  const int r16 = lane & 15, q8 = (lane >> 4) * 8;
  int offA[MF2];
#pragma unroll
  for (int mi = 0; mi < MF2; ++mi) {
    const int row = wrow + mi * 16 + r16;
    offA[mi] = row * 32 + (q8 ^ (((row >> 1) & 3) << 3));
  }
  int offB0, offB1, offB2, offB3;
  {
    const int r0 = wcol + 0 * 16 + r16;
    const int r1 = wcol + 1 * 16 + r16;
    const int r2 = wcol + 2 * 16 + r16;
    const int r3 = wcol + 3 * 16 + r16;
    offB0 = r0 * 32 + (q8 ^ (((r0 >> 1) & 3) << 3));
    offB1 = r1 * 32 + (q8 ^ (((r1 >> 1) & 3) << 3));
    offB2 = r2 * 32 + (q8 ^ (((r2 >> 1) & 3) << 3));
    offB3 = r3 * 32 + (q8 ^ (((r3 >> 1) & 3) << 3));
  }

  auto rdA = [&](short8* a, int d, int h) {
    const u16* P = sm + d * DBUF + h * HSTEP;
#pragma unroll
    for (int mi = 0; mi < MF2; ++mi) a[mi] = *(const short8*)(P + offA[mi]);
  };
  auto rdBlo = [&](short8* b, int d, int h) {
    const u16* P = sm + d * DBUF + h * HSTEP + APAN;
    b[0] = *(const short8*)(P + offB0);
    b[1] = *(const short8*)(P + offB1);
  };
  auto rdBhi = [&](short8* b, int d, int h) {
    const u16* P = sm + d * DBUF + h * HSTEP + APAN;
    b[0] = *(const short8*)(P + offB2);
    b[1] = *(const short8*)(P + offB3);
  };

  f32x4 acc0[MF2][2] = {};   // n-frags 0,1
  f32x4 acc1[MF2][2] = {};   // n-frags 2,3
  const bool vblk = (MODE == 1) && (blockN >= 2048);

  auto MMA = [&](short8* a2, short8* b2, f32x4 (&ac)[MF2][2]) {
    __builtin_amdgcn_s_setprio(1);
    if (vblk) {
#pragma unroll
      for (int mi = 0; mi < MF2; ++mi)
#pragma unroll
        for (int j = 0; j < 2; ++j)
          ac[mi][j] = __builtin_amdgcn_mfma_f32_16x16x32_bf16(
              b2[j], a2[mi], ac[mi][j], 0, 0, 0);
    } else {
#pragma unroll
      for (int mi = 0; mi < MF2; ++mi)
#pragma unroll
        for (int j = 0; j < 2; ++j)
          ac[mi][j] = __builtin_amdgcn_mfma_f32_16x16x32_bf16(
              a2[mi], b2[j], ac[mi][j], 0, 0, 0);
    }
    __builtin_amdgcn_s_setprio(0);
  };

  const int NT = K >> 6;   // K-tiles (BK=64)

  // ---- prologue: stage all 4 halves of tile 0 (issue order = ledger order)
  STAGEA(0, 0); STAGEB(0, 0); STAGEA(0, 1); STAGEB(0, 1);

  short8 a[MF2], bv0[2], bv1[2];
  for (int t = 0; t < NT; ++t) {
    const int d = t & 1;
    const bool more = (t + 1 < NT);

    // ---- P1 (k0, n-lo)
    asm volatile("s_waitcnt vmcnt(%0)" :: "i"(LEAVE) : "memory");
    __builtin_amdgcn_s_barrier();
    __builtin_amdgcn_sched_barrier(0);
    rdA(a, d, 0);
    rdBlo(bv0, d, 0);
    if (more) STAGEA(t + 1, 0);
    MMA(a, bv0, acc0);

    // ---- P2 (k0, n-hi) — no wait/barrier
    rdBhi(bv1, d, 0);
    if (more) STAGEB(t + 1, 0);
    MMA(a, bv1, acc1);

    // ---- P3 (k1, n-lo)
    if (more) asm volatile("s_waitcnt vmcnt(%0)" :: "i"(LEAVE) : "memory");
    else      asm volatile("s_waitcnt vmcnt(0)" ::: "memory");
    __builtin_amdgcn_s_barrier();
    __builtin_amdgcn_sched_barrier(0);
    rdA(a, d, 1);
    rdBlo(bv0, d, 1);
    if (more) STAGEA(t + 1, 1);
    MMA(a, bv0, acc0);

    // ---- P4 (k1, n-hi) — no wait/barrier
    rdBhi(bv1, d, 1);
    if (more) STAGEB(t + 1, 1);
    MMA(a, bv1, acc1);
  }

  // ---- epilogue: C/D layout col=lane&15, row=(lane>>4)*4+i
  const int cr = lane & 15, rr0 = (lane >> 4) * 4;
  OutT* Cb = C + (size_t)bz * sC;
  if (vblk) {
    // operand-swapped: D[row = W-side (d)][col = X-side (t, within M)]
#pragma unroll
    for (int nj = 0; nj < 4; ++nj) {
#pragma unroll
      for (int mi = 0; mi < MF2; ++mi) {
        f32x4 v = (nj < 2) ? acc0[mi][nj & 1] : acc1[mi][nj & 1];
        const int tg = blockM + wrow + mi * 16 + cr;   // global M row
        const int b  = tg >> 11, t0 = tg & 2047;
        const int d0 = blockN - 2048 + wcol + nj * 16 + rr0;
#pragma unroll
        for (int i = 0; i < 4; ++i) {
          const float bval = HAS_BIAS ? bias[2048 + d0 + i] : 0.0f;
          out3[((size_t)b * 1024 + d0 + i) * 2048 + t0] = f2bf(v[i] + bval);
        }
      }
    }
  } else {
#pragma unroll
    for (int nj = 0; nj < 4; ++nj) {
      const int colg = blockN + wcol + nj * 16 + cr;
      const float bval = HAS_BIAS ? bias[colg] : 0.0f;
#pragma unroll
      for (int mi = 0; mi < MF2; ++mi) {
        f32x4 v = (nj < 2) ? acc0[mi][nj & 1] : acc1[mi][nj & 1];
        const int rowg = blockM + wrow + mi * 16 + rr0;
        if constexpr (MODE == 0) {
#pragma unroll
          for (int i = 0; i < 4; ++i)
            store_out(&Cb[(size_t)(rowg + i) * ldc + colg], v[i] * scale + bval);
        } else {
          u16* dst = (colg < 1024) ? (u16*)Cb : out2;
          const int c2 = colg & 1023;
#pragma unroll
          for (int i = 0; i < 4; ++i)
            dst[(size_t)(rowg + i) * 1024 + c2] = f2bf(v[i] + bval);
        }
      }
    }
  }
}

// ---------------------------------------------------------------------------
// aux kernels
// ---------------------------------------------------------------------------
__global__ __launch_bounds__(256) void cvt_f32_bf16(
    const float* __restrict__ in, u16* __restrict__ out, int n4)
{
  int i = blockIdx.x * 256 + threadIdx.x;
  if (i >= n4) return;
  float4 v = ((const float4*)in)[i];
  uint2 u;
  u.x = (unsigned)f2bf(v.x) | ((unsigned)f2bf(v.y) << 16);
  u.y = (unsigned)f2bf(v.z) | ((unsigned)f2bf(v.w) << 16);
  ((uint2*)out)[i] = u;
}

__global__ __launch_bounds__(256) void transpose_cvt(
    const float* __restrict__ W, u16* __restrict__ Wt)
{
  __shared__ u16 tile[32][33];
  const int tx = threadIdx.x;
  const int ty = threadIdx.y;
  const int bx = blockIdx.x * 32;
  const int by = blockIdx.y * 32;
#pragma unroll
  for (int j = 0; j < 4; ++j) {
    int d = by + ty * 4 + j;
    tile[ty * 4 + j][tx] = f2bf(W[(size_t)d * DD + bx + tx]);
  }
  __syncthreads();
#pragma unroll
  for (int j = 0; j < 4; ++j) {
    int f = bx + ty * 4 + j;
    Wt[(size_t)f * DD + by + tx] = tile[tx][ty * 4 + j];
  }
}

__global__ __launch_bounds__(256) void concat_bias(
    const float* __restrict__ bq, const float* __restrict__ bk,
    const float* __restrict__ bv, float* __restrict__ out)
{
  int i = blockIdx.x * 256 + threadIdx.x;   // 3072 total
  const float* src = (i < 1024) ? bq : ((i < 2048) ? bk : bv);
  out[i] = src[i & 1023];
}

__global__ __launch_bounds__(256) void softmax_inplace(float* __restrict__ S)
{
  const int tid = threadIdx.x;
  float* rp = S + (size_t)blockIdx.x * SS;

  float4 v0 = ((const float4*)rp)[tid];
  float4 v1 = ((const float4*)rp)[tid + 256];

  float m = fmaxf(fmaxf(fmaxf(v0.x, v0.y), fmaxf(v0.z, v0.w)),
                  fmaxf(fmaxf(v1.x, v1.y), fmaxf(v1.z, v1.w)));
#pragma unroll
  for (int off = 32; off; off >>= 1) m = fmaxf(m, __shfl_xor(m, off));

  __shared__ float smax[4];
  __shared__ float ssum[4];
  const int wave = tid >> 6, lane = tid & 63;
  if (lane == 0) smax[wave] = m;
  __syncthreads();
  m = fmaxf(fmaxf(smax[0], smax[1]), fmaxf(smax[2], smax[3]));

  float e[8];
  e[0] = __expf(v0.x - m); e[1] = __expf(v0.y - m);
  e[2] = __expf(v0.z - m); e[3] = __expf(v0.w - m);
  e[4] = __expf(v1.x - m); e[5] = __expf(v1.y - m);
  e[6] = __expf(v1.z - m); e[7] = __expf(v1.w - m);
  float s = e[0] + e[1] + e[2] + e[3] + e[4] + e[5] + e[6] + e[7];
#pragma unroll
  for (int off = 32; off; off >>= 1) s += __shfl_xor(s, off);
  if (lane == 0) ssum[wave] = s;
  __syncthreads();
  float inv = 1.0f / (ssum[0] + ssum[1] + ssum[2] + ssum[3]);

  uint2 u0, u1;
  u0.x = (unsigned)f2bf(e[0] * inv) | ((unsigned)f2bf(e[1] * inv) << 16);
  u0.y = (unsigned)f2bf(e[2] * inv) | ((unsigned)f2bf(e[3] * inv) << 16);
  u1.x = (unsigned)f2bf(e[4] * inv) | ((unsigned)f2bf(e[5] * inv) << 16);
  u1.y = (unsigned)f2bf(e[6] * inv) | ((unsigned)f2bf(e[7] * inv) << 16);
  ((uint2*)rp)[tid]       = u0;
  ((uint2*)rp)[tid + 256] = u1;
}

// ---------------------------------------------------------------------------
extern "C" void kernel_launch(void* const* d_in, const int* in_sizes, int n_in,
                              void* d_out, int out_size, void* d_ws, size_t ws_size,
                              hipStream_t stream) {
  (void)in_sizes; (void)n_in; (void)out_size; (void)ws_size;
  const float* X  = (const float*)d_in[0];
  const float* Wq = (const float*)d_in[1];
  const float* bq = (const float*)d_in[2];
  const float* Wk = (const float*)d_in[3];
  const float* bk = (const float*)d_in[4];
  const float* Wv = (const float*)d_in[5];
  const float* bv = (const float*)d_in[6];
  const float* Wo = (const float*)d_in[7];
  const float* bo = (const float*)d_in[8];

  char* ws = (char*)d_ws;
  const size_t MBy = 1ull << 20;
  u16*   Xbf   = (u16*)(ws + 0);          // 16 MB [8192][1024]
  u16*   WtAll = (u16*)(ws + 16 * MBy);   //  6 MB [3072][1024]
  u16*   Wto   = (u16*)(ws + 22 * MBy);   //  2 MB [1024][1024]
  u16*   Qb    = (u16*)(ws + 24 * MBy);   // 16 MB [8192][1024]
  u16*   Kb    = (u16*)(ws + 40 * MBy);   // 16 MB
  u16*   Vt    = (u16*)(ws + 56 * MBy);   // 16 MB [4][1024][2048]
  float* Sf    = (float*)(ws + 72 * MBy); // 64 MB [4][2048][2048]
  float* bqkv  = (float*)(ws + 72 * MBy); // aliases Sf (consumed before QK^T)
  u16*   Ctx   = (u16*)(ws + 136 * MBy);  // 16 MB [8192][1024]

  // 1. conversions + packing
  cvt_f32_bf16<<<dim3((BB * SS * DD / 4) / 256), 256, 0, stream>>>(X, Xbf, BB * SS * DD / 4);
  dim3 tb(32, 8);
  transpose_cvt<<<dim3(32, 32), tb, 0, stream>>>(Wq, WtAll);
  transpose_cvt<<<dim3(32, 32), tb, 0, stream>>>(Wk, WtAll + 1024 * 1024);
  transpose_cvt<<<dim3(32, 32), tb, 0, stream>>>(Wv, WtAll + 2 * 1024 * 1024);
  transpose_cvt<<<dim3(32, 32), tb, 0, stream>>>(Wo, Wto);
  concat_bias<<<dim3(12), 256, 0, stream>>>(bq, bk, bv, bqkv);

  // 2. merged QKV projection: [8192][3072]; V via operand-swap (384 blocks)
  gemm8p<u16, 256, 1, true><<<dim3(12, 32, 1), 512, 0, stream>>>(
      Xbf, 0, DD * 2, WtAll, 0, DD * 2,
      Qb, 0, 0, bqkv, 1.0f, DD, Kb, Vt);

  // 3. scores = Q K^T / 8 (fp32, 256 blocks)
  gemm8p<float, 256, 0, false><<<dim3(8, 8, BB), 512, 0, stream>>>(
      Qb, (size_t)SS * DD, DD * 2, Kb, (size_t)SS * DD, DD * 2,
      Sf, (size_t)SS * SS, SS, nullptr, 0.125f, DD, nullptr, nullptr);

  // 4. softmax rows (in-place fp32 -> bf16)
  softmax_inplace<<<dim3(BB * SS), 256, 0, stream>>>(Sf);

  // 5. ctx = P V  (P bf16 rows of 8192 B; B = Vt [1024][2048]; 256 blocks)
  gemm8p<u16, 128, 0, false><<<dim3(4, 16, BB), 512, 0, stream>>>(
      (const u16*)Sf, (size_t)SS * 2 * SS, 2 * SS * 2,
      Vt, (size_t)DD * SS, SS * 2,
      Ctx, (size_t)SS * DD, DD, nullptr, 1.0f, SS, nullptr, nullptr);

  // 6. out = ctx Wo^T + bo (fp32, 256 blocks)
  gemm8p<float, 128, 0, true><<<dim3(4, 64, 1), 512, 0, stream>>>(
      Ctx, 0, DD * 2, Wto, 0, DD * 2,
      (float*)d_out, 0, DD, bo, 1.0f, DD, nullptr, nullptr);
}

// Round 9
// 209.683 us; speedup vs baseline: 2.2329x; 2.2234x over previous
//
#include <hip/hip_runtime.h>
#include <cstdint>
#include <cstddef>

typedef unsigned short u16;
typedef __attribute__((ext_vector_type(8))) short short8;
typedef __attribute__((ext_vector_type(4))) float f32x4;

#define BB 4
#define SS 2048
#define DD 1024

__device__ __forceinline__ u16 f2bf(float f) {
  union { float f; unsigned u; } x; x.f = f;
  unsigned r = x.u + 0x7FFFu + ((x.u >> 16) & 1u);
  return (u16)(r >> 16);
}

__device__ __forceinline__ void gld_lds16(const void* g, void* l) {
  __builtin_amdgcn_global_load_lds(
      (const __attribute__((address_space(1))) void*)g,
      (__attribute__((address_space(3))) void*)l, 16, 0, 0);
}

__device__ __forceinline__ void store_out(float* p, float v) { *p = v; }
__device__ __forceinline__ void store_out(u16* p, float v) { *p = f2bf(v); }

// ---------------------------------------------------------------------------
// 4-phase counted-vmcnt GEMM, 128x256 tile, BK=64, 8 waves (2M x 4N),
// per-wave tile 64x64, acc = 64 regs (4x4 f32x4).
// REGISTER BUDGET (rounds 6-8 lesson): 512-thread block = 2 waves/SIMD
// ALWAYS -> hard 256 reg/wave cap (VGPR+AGPR), independent of
// __launch_bounds__ arg2. BM=256 (128-reg acc) + this schedule's liveness
// spilled ~600 MB/dispatch. BM=128 keeps total ~170 regs -> no spill.
// LDS double-buffered, each buf = {Ak0(8K), Bk0(16K), Ak1, Bk1} = 48 KB.
// Per K-tile: P1 {vmcnt(3); barrier; read A(k0)+B(lo,k0); stage Ak0(t+1);
// MFMA}, P2 {read B(hi,k0); stage Bk0(t+1); MFMA}, P3/P4 mirror on k1.
// 6 loads/tile; vmcnt(3) leaves the newest 3 in flight (never 0 mid-loop);
// stage->use distance 3-4 phases. WAR: stage(t+1) writes opposite buffer;
// reuse separated by >=4 barriers.
// LDS swizzle (both-sides involution, 0 conflicts): cbyte ^= ((row>>1)&3)<<4.
// MODE 0: C[row][col] = acc*scale (+bias[col]).
// MODE 1 (QKV): x-blk 0-3 -> C (Q), 4-7 -> out2 (K); 8-11 (V) use
// operand-swapped MFMA -> transposed tile -> coalesced Vt[b][d][t] stores.
// Grid: x=N/256, y=M/128, z=batch; nwg % 8 == 0. K % 64 == 0, K >= 128.
// ---------------------------------------------------------------------------
template<typename OutT, int MODE, bool HAS_BIAS>
__global__ __launch_bounds__(512, 1) void gemm8p(
    const u16* __restrict__ A, size_t sA, int ldaB,
    const u16* __restrict__ B, size_t sB, int ldbB,
    OutT* __restrict__ C, size_t sC, int ldc,
    const float* __restrict__ bias, float scale, int K,
    u16* __restrict__ out2, u16* __restrict__ out3)
{
  constexpr int APAN  = 128 * 32;         // A panel elems (per k-half, 8 KB)
  constexpr int HSTEP = APAN + 8192;      // A+B panel pair (24 KB)
  constexpr int DBUF  = 2 * HSTEP;        // one double-buffer half (48 KB)
  __shared__ u16 sm[4 * HSTEP];           // 96 KB

  // ---- XCD-aware block swizzle (bijective: nwg % 8 == 0)
  const int gx = gridDim.x, gy = gridDim.y;
  const int nwg = gx * gy * gridDim.z;
  const int flat = blockIdx.x + gx * (blockIdx.y + gy * blockIdx.z);
  const int swz = (flat & 7) * (nwg >> 3) + (flat >> 3);
  const int bz  = swz / (gx * gy);
  const int rem = swz - bz * (gx * gy);
  const int by  = rem / gx;
  const int bx  = rem - by * gx;
  const int blockM = by * 128, blockN = bx * 256;

  const char* Abase = (const char*)(A + (size_t)bz * sA);
  const char* Bbase = (const char*)(B + (size_t)bz * sB);

  const int tid  = threadIdx.x;
  const int wave = tid >> 6, lane = tid & 63;
  const int wrow = (wave >> 2) * 64;
  const int wcol = (wave & 3) * 64;

  // ---- staging coords: thread -> (row 0..127, swizzled col-byte)
  const int sr  = tid >> 2;
  const int scb = ((tid & 3) * 16) ^ (((sr >> 1) & 3) << 4);
  const char* gA0 = Abase + (size_t)(blockM + sr)       * ldaB + scb;
  const char* gB0 = Bbase + (size_t)(blockN + sr)       * ldbB + scb;
  const char* gB1 = Bbase + (size_t)(blockN + sr + 128) * ldbB + scb;
  const int ldsw = wave * 512;   // wave-uniform LDS dest base (elems)

  // stage half h (0:k0, 1:k1) of K-tile t1 into buf (t1&1)
  auto STAGEA = [&](int t1, int h) {
    u16* Ap = sm + (t1 & 1) * DBUF + h * HSTEP;
    const int kb = t1 * 128 + h * 64;
    gld_lds16(gA0 + kb, Ap + ldsw);
  };
  auto STAGEB = [&](int t1, int h) {
    u16* Bp = sm + (t1 & 1) * DBUF + h * HSTEP + APAN;
    const int kb = t1 * 128 + h * 64;
    gld_lds16(gB0 + kb, Bp + ldsw);
    gld_lds16(gB1 + kb, Bp + 4096 + ldsw);
  };

  // ---- precomputed swizzled frag read offsets (elems, panel-relative)
  const int r16 = lane & 15, q8 = (lane >> 4) * 8;
  int offA[4];
#pragma unroll
  for (int mi = 0; mi < 4; ++mi) {
    const int row = wrow + mi * 16 + r16;
    offA[mi] = row * 32 + (q8 ^ (((row >> 1) & 3) << 3));
  }
  int offB0, offB1, offB2, offB3;
  {
    const int r0 = wcol + 0 * 16 + r16;
    const int r1 = wcol + 1 * 16 + r16;
    const int r2 = wcol + 2 * 16 + r16;
    const int r3 = wcol + 3 * 16 + r16;
    offB0 = r0 * 32 + (q8 ^ (((r0 >> 1) & 3) << 3));
    offB1 = r1 * 32 + (q8 ^ (((r1 >> 1) & 3) << 3));
    offB2 = r2 * 32 + (q8 ^ (((r2 >> 1) & 3) << 3));
    offB3 = r3 * 32 + (q8 ^ (((r3 >> 1) & 3) << 3));
  }

  auto rdA = [&](short8* a, int d, int h) {
    const u16* P = sm + d * DBUF + h * HSTEP;
#pragma unroll
    for (int mi = 0; mi < 4; ++mi) a[mi] = *(const short8*)(P + offA[mi]);
  };
  auto rdBlo = [&](short8* b, int d, int h) {
    const u16* P = sm + d * DBUF + h * HSTEP + APAN;
    b[0] = *(const short8*)(P + offB0);
    b[1] = *(const short8*)(P + offB1);
  };
  auto rdBhi = [&](short8* b, int d, int h) {
    const u16* P = sm + d * DBUF + h * HSTEP + APAN;
    b[0] = *(const short8*)(P + offB2);
    b[1] = *(const short8*)(P + offB3);
  };

  f32x4 acc0[4][2] = {};   // n-frags 0,1
  f32x4 acc1[4][2] = {};   // n-frags 2,3
  const bool vblk = (MODE == 1) && (blockN >= 2048);

  auto MMA = [&](short8* a2, short8* b2, f32x4 (&ac)[4][2]) {
    __builtin_amdgcn_s_setprio(1);
    if (vblk) {
#pragma unroll
      for (int mi = 0; mi < 4; ++mi)
#pragma unroll
        for (int j = 0; j < 2; ++j)
          ac[mi][j] = __builtin_amdgcn_mfma_f32_16x16x32_bf16(
              b2[j], a2[mi], ac[mi][j], 0, 0, 0);
    } else {
#pragma unroll
      for (int mi = 0; mi < 4; ++mi)
#pragma unroll
        for (int j = 0; j < 2; ++j)
          ac[mi][j] = __builtin_amdgcn_mfma_f32_16x16x32_bf16(
              a2[mi], b2[j], ac[mi][j], 0, 0, 0);
    }
    __builtin_amdgcn_s_setprio(0);
  };

  const int NT = K >> 6;   // K-tiles (BK=64)

  // ---- prologue: stage all 4 halves of tile 0 (6 loads, ledger order)
  STAGEA(0, 0); STAGEB(0, 0); STAGEA(0, 1); STAGEB(0, 1);

  short8 a[4], bv0[2], bv1[2];
  for (int t = 0; t < NT; ++t) {
    const int d = t & 1;
    const bool more = (t + 1 < NT);

    // ---- P1 (k0, n-lo): force Ak0,Bk0 landed; leave k1 halves in flight
    asm volatile("s_waitcnt vmcnt(3)" ::: "memory");
    __builtin_amdgcn_s_barrier();
    __builtin_amdgcn_sched_barrier(0);
    rdA(a, d, 0);
    rdBlo(bv0, d, 0);
    if (more) STAGEA(t + 1, 0);
    MMA(a, bv0, acc0);

    // ---- P2 (k0, n-hi) — no wait/barrier
    rdBhi(bv1, d, 0);
    if (more) STAGEB(t + 1, 0);
    MMA(a, bv1, acc1);

    // ---- P3 (k1, n-lo)
    if (more) asm volatile("s_waitcnt vmcnt(3)" ::: "memory");
    else      asm volatile("s_waitcnt vmcnt(0)" ::: "memory");
    __builtin_amdgcn_s_barrier();
    __builtin_amdgcn_sched_barrier(0);
    rdA(a, d, 1);
    rdBlo(bv0, d, 1);
    if (more) STAGEA(t + 1, 1);
    MMA(a, bv0, acc0);

    // ---- P4 (k1, n-hi) — no wait/barrier
    rdBhi(bv1, d, 1);
    if (more) STAGEB(t + 1, 1);
    MMA(a, bv1, acc1);
  }

  // ---- epilogue: C/D layout col=lane&15, row=(lane>>4)*4+i
  const int cr = lane & 15, rr0 = (lane >> 4) * 4;
  OutT* Cb = C + (size_t)bz * sC;
  if (vblk) {
    // operand-swapped: D[row = W-side (d)][col = X-side (t, within M)]
#pragma unroll
    for (int nj = 0; nj < 4; ++nj) {
#pragma unroll
      for (int mi = 0; mi < 4; ++mi) {
        f32x4 v = (nj < 2) ? acc0[mi][nj & 1] : acc1[mi][nj & 1];
        const int tg = blockM + wrow + mi * 16 + cr;   // global M row
        const int b  = tg >> 11, t0 = tg & 2047;
        const int d0 = blockN - 2048 + wcol + nj * 16 + rr0;
#pragma unroll
        for (int i = 0; i < 4; ++i) {
          const float bval = HAS_BIAS ? bias[2048 + d0 + i] : 0.0f;
          out3[((size_t)b * 1024 + d0 + i) * 2048 + t0] = f2bf(v[i] + bval);
        }
      }
    }
  } else {
#pragma unroll
    for (int nj = 0; nj < 4; ++nj) {
      const int colg = blockN + wcol + nj * 16 + cr;
      const float bval = HAS_BIAS ? bias[colg] : 0.0f;
#pragma unroll
      for (int mi = 0; mi < 4; ++mi) {
        f32x4 v = (nj < 2) ? acc0[mi][nj & 1] : acc1[mi][nj & 1];
        const int rowg = blockM + wrow + mi * 16 + rr0;
        if constexpr (MODE == 0) {
#pragma unroll
          for (int i = 0; i < 4; ++i)
            store_out(&Cb[(size_t)(rowg + i) * ldc + colg], v[i] * scale + bval);
        } else {
          u16* dst = (colg < 1024) ? (u16*)Cb : out2;
          const int c2 = colg & 1023;
#pragma unroll
          for (int i = 0; i < 4; ++i)
            dst[(size_t)(rowg + i) * 1024 + c2] = f2bf(v[i] + bval);
        }
      }
    }
  }
}

// ---------------------------------------------------------------------------
// aux kernels
// ---------------------------------------------------------------------------
__global__ __launch_bounds__(256) void cvt_f32_bf16(
    const float* __restrict__ in, u16* __restrict__ out, int n4)
{
  int i = blockIdx.x * 256 + threadIdx.x;
  if (i >= n4) return;
  float4 v = ((const float4*)in)[i];
  uint2 u;
  u.x = (unsigned)f2bf(v.x) | ((unsigned)f2bf(v.y) << 16);
  u.y = (unsigned)f2bf(v.z) | ((unsigned)f2bf(v.w) << 16);
  ((uint2*)out)[i] = u;
}

__global__ __launch_bounds__(256) void transpose_cvt(
    const float* __restrict__ W, u16* __restrict__ Wt)
{
  __shared__ u16 tile[32][33];
  const int tx = threadIdx.x;
  const int ty = threadIdx.y;
  const int bx = blockIdx.x * 32;
  const int by = blockIdx.y * 32;
#pragma unroll
  for (int j = 0; j < 4; ++j) {
    int d = by + ty * 4 + j;
    tile[ty * 4 + j][tx] = f2bf(W[(size_t)d * DD + bx + tx]);
  }
  __syncthreads();
#pragma unroll
  for (int j = 0; j < 4; ++j) {
    int f = bx + ty * 4 + j;
    Wt[(size_t)f * DD + by + tx] = tile[tx][ty * 4 + j];
  }
}

__global__ __launch_bounds__(256) void concat_bias(
    const float* __restrict__ bq, const float* __restrict__ bk,
    const float* __restrict__ bv, float* __restrict__ out)
{
  int i = blockIdx.x * 256 + threadIdx.x;   // 3072 total
  const float* src = (i < 1024) ? bq : ((i < 2048) ? bk : bv);
  out[i] = src[i & 1023];
}

__global__ __launch_bounds__(256) void softmax_inplace(float* __restrict__ S)
{
  const int tid = threadIdx.x;
  float* rp = S + (size_t)blockIdx.x * SS;

  float4 v0 = ((const float4*)rp)[tid];
  float4 v1 = ((const float4*)rp)[tid + 256];

  float m = fmaxf(fmaxf(fmaxf(v0.x, v0.y), fmaxf(v0.z, v0.w)),
                  fmaxf(fmaxf(v1.x, v1.y), fmaxf(v1.z, v1.w)));
#pragma unroll
  for (int off = 32; off; off >>= 1) m = fmaxf(m, __shfl_xor(m, off));

  __shared__ float smax[4];
  __shared__ float ssum[4];
  const int wave = tid >> 6, lane = tid & 63;
  if (lane == 0) smax[wave] = m;
  __syncthreads();
  m = fmaxf(fmaxf(smax[0], smax[1]), fmaxf(smax[2], smax[3]));

  float e[8];
  e[0] = __expf(v0.x - m); e[1] = __expf(v0.y - m);
  e[2] = __expf(v0.z - m); e[3] = __expf(v0.w - m);
  e[4] = __expf(v1.x - m); e[5] = __expf(v1.y - m);
  e[6] = __expf(v1.z - m); e[7] = __expf(v1.w - m);
  float s = e[0] + e[1] + e[2] + e[3] + e[4] + e[5] + e[6] + e[7];
#pragma unroll
  for (int off = 32; off; off >>= 1) s += __shfl_xor(s, off);
  if (lane == 0) ssum[wave] = s;
  __syncthreads();
  float inv = 1.0f / (ssum[0] + ssum[1] + ssum[2] + ssum[3]);

  uint2 u0, u1;
  u0.x = (unsigned)f2bf(e[0] * inv) | ((unsigned)f2bf(e[1] * inv) << 16);
  u0.y = (unsigned)f2bf(e[2] * inv) | ((unsigned)f2bf(e[3] * inv) << 16);
  u1.x = (unsigned)f2bf(e[4] * inv) | ((unsigned)f2bf(e[5] * inv) << 16);
  u1.y = (unsigned)f2bf(e[6] * inv) | ((unsigned)f2bf(e[7] * inv) << 16);
  ((uint2*)rp)[tid]       = u0;
  ((uint2*)rp)[tid + 256] = u1;
}

// ---------------------------------------------------------------------------
extern "C" void kernel_launch(void* const* d_in, const int* in_sizes, int n_in,
                              void* d_out, int out_size, void* d_ws, size_t ws_size,
                              hipStream_t stream) {
  (void)in_sizes; (void)n_in; (void)out_size; (void)ws_size;
  const float* X  = (const float*)d_in[0];
  const float* Wq = (const float*)d_in[1];
  const float* bq = (const float*)d_in[2];
  const float* Wk = (const float*)d_in[3];
  const float* bk = (const float*)d_in[4];
  const float* Wv = (const float*)d_in[5];
  const float* bv = (const float*)d_in[6];
  const float* Wo = (const float*)d_in[7];
  const float* bo = (const float*)d_in[8];

  char* ws = (char*)d_ws;
  const size_t MBy = 1ull << 20;
  u16*   Xbf   = (u16*)(ws + 0);          // 16 MB [8192][1024]
  u16*   WtAll = (u16*)(ws + 16 * MBy);   //  6 MB [3072][1024]
  u16*   Wto   = (u16*)(ws + 22 * MBy);   //  2 MB [1024][1024]
  u16*   Qb    = (u16*)(ws + 24 * MBy);   // 16 MB [8192][1024]
  u16*   Kb    = (u16*)(ws + 40 * MBy);   // 16 MB
  u16*   Vt    = (u16*)(ws + 56 * MBy);   // 16 MB [4][1024][2048]
  float* Sf    = (float*)(ws + 72 * MBy); // 64 MB [4][2048][2048]
  float* bqkv  = (float*)(ws + 72 * MBy); // aliases Sf (consumed before QK^T)
  u16*   Ctx   = (u16*)(ws + 136 * MBy);  // 16 MB [8192][1024]

  // 1. conversions + packing
  cvt_f32_bf16<<<dim3((BB * SS * DD / 4) / 256), 256, 0, stream>>>(X, Xbf, BB * SS * DD / 4);
  dim3 tb(32, 8);
  transpose_cvt<<<dim3(32, 32), tb, 0, stream>>>(Wq, WtAll);
  transpose_cvt<<<dim3(32, 32), tb, 0, stream>>>(Wk, WtAll + 1024 * 1024);
  transpose_cvt<<<dim3(32, 32), tb, 0, stream>>>(Wv, WtAll + 2 * 1024 * 1024);
  transpose_cvt<<<dim3(32, 32), tb, 0, stream>>>(Wo, Wto);
  concat_bias<<<dim3(12), 256, 0, stream>>>(bq, bk, bv, bqkv);

  // 2. merged QKV projection: [8192][3072]; V via operand-swap (768 blocks)
  gemm8p<u16, 1, true><<<dim3(12, 64, 1), 512, 0, stream>>>(
      Xbf, 0, DD * 2, WtAll, 0, DD * 2,
      Qb, 0, 0, bqkv, 1.0f, DD, Kb, Vt);

  // 3. scores = Q K^T / 8 (fp32, 512 blocks)
  gemm8p<float, 0, false><<<dim3(8, 16, BB), 512, 0, stream>>>(
      Qb, (size_t)SS * DD, DD * 2, Kb, (size_t)SS * DD, DD * 2,
      Sf, (size_t)SS * SS, SS, nullptr, 0.125f, DD, nullptr, nullptr);

  // 4. softmax rows (in-place fp32 -> bf16)
  softmax_inplace<<<dim3(BB * SS), 256, 0, stream>>>(Sf);

  // 5. ctx = P V  (P bf16 rows of 8192 B; B = Vt [1024][2048]; 256 blocks)
  gemm8p<u16, 0, false><<<dim3(4, 16, BB), 512, 0, stream>>>(
      (const u16*)Sf, (size_t)SS * 2 * SS, 2 * SS * 2,
      Vt, (size_t)DD * SS, SS * 2,
      Ctx, (size_t)SS * DD, DD, nullptr, 1.0f, SS, nullptr, nullptr);

  // 6. out = ctx Wo^T + bo (fp32, 256 blocks)
  gemm8p<float, 0, true><<<dim3(4, 64, 1), 512, 0, stream>>>(
      Ctx, 0, DD * 2, Wto, 0, DD * 2,
      (float*)d_out, 0, DD, bo, 1.0f, DD, nullptr, nullptr);
}